// Round 1
// baseline (260.900 us; speedup 1.0000x reference)
//
#include <hip/hip_runtime.h>

// SNN forward scan: B=64, N=1024, T=512. Row = (b*N+n), x[row*512 + t].
// One thread per row; 64-thread (1-wave) blocks; LDS-staged coalesced I/O.
//
// Numerics: must be BIT-EXACT vs the float32 NumPy reference (output is a
// 0/1 threshold — one ulp flip cascades). All mul+add pairs use __fmul_rn/
// __fadd_rn to forbid FMA contraction.
#pragma clang fp contract(off)

#define ROWS    64      // rows per block == threads per block (1 wave)
#define T_LEN   512
#define CHUNK   64      // timesteps staged per tile
#define NCHUNK  (T_LEN / CHUNK)            // 8
#define STRIDE  (CHUNK + 4)                // 68 floats: 16B-aligned rows, balanced banks
#define NVEC    (ROWS * CHUNK / 4 / ROWS)  // 16 float4 per thread per chunk
#define NPARAM  1024

__global__ __launch_bounds__(ROWS) void snn_fwd(
    const float* __restrict__ x,
    const float* __restrict__ beta,
    const float* __restrict__ p,
    const float* __restrict__ bparam,
    float* __restrict__ out)
{
    __shared__ float inbuf[ROWS * STRIDE];   // 17,408 B
    __shared__ float outbuf[ROWS * STRIDE];  // 17,408 B  (34.8 KiB total -> 4 blocks/CU)

    const int tid     = threadIdx.x;
    const int rowBase = blockIdx.x * ROWS;
    const int n       = (rowBase + tid) & (NPARAM - 1);

    // clamped effective params (clip bounds as float32, same as np)
    const float beta_c = fminf(fmaxf(beta[n], 0.001f), 0.999f);
    const float p_c    = fminf(fabsf(p[n]), 0.999f);
    const float b_c    = fminf(fmaxf(fabsf(bparam[n]), 0.001f), 1.0f);

    // recurrence state
    float mem = 0.0f, refac = 2.0f, a = 0.0f, vth = 1.0f, ps = 0.0f;

    const float4* __restrict__ xv = (const float4*)x;   // row stride = 128 float4
    float4* __restrict__ ov       = (float4*)out;

    // staging map: flat float4 f = it*64 + tid; local row = it*4 + (tid>>4),
    // t4 = tid&15 -> lanes 0..15 read one row's 256 B contiguously (coalesced).
    const int t4c   = tid & 15;
    const int rquad = tid >> 4;
    const int gq    = (rowBase + rquad) * (T_LEN / 4) + t4c;  // global float4 base
    const int lq    = rquad * STRIDE + t4c * 4;               // LDS float base

    float4 ld[NVEC];

    auto loadChunk = [&](int k) {
        const int base = gq + k * (CHUNK / 4);
        #pragma unroll
        for (int it = 0; it < NVEC; ++it)
            ld[it] = xv[base + it * 4 * (T_LEN / 4)];   // +4 rows per it
    };

    auto stage = [&]() {
        #pragma unroll
        for (int it = 0; it < NVEC; ++it)
            *(float4*)&inbuf[lq + it * 4 * STRIDE] = ld[it];
    };

    auto readout = [&](int k) {
        const int base = gq + k * (CHUNK / 4);
        #pragma unroll
        for (int it = 0; it < NVEC; ++it) {
            float4 sv = *(const float4*)&outbuf[lq + it * 4 * STRIDE];
            ov[base + it * 4 * (T_LEN / 4)] = sv;
        }
    };

    // one recurrence step; returns spike (0.0/1.0)
    auto step = [&](float xt) -> float {
        refac = (ps > 0.0f) ? 0.0f : refac;           // spike-triggered reset
        const float ic = (refac < 2.0f) ? 0.0f : xt;  // refractory input mask
        refac += 1.0f;
        const float nm   = __fadd_rn(__fmul_rn(mem, beta_c), ic);  // leaky integrate
        const float diff = __fsub_rn(nm, vth);
        const float s    = (diff > 0.0f) ? 1.0f : 0.0f;
        mem = (diff > 0.0f) ? 0.0f : nm;              // reset-to-zero on spike
        a   = __fadd_rn(__fmul_rn(p_c, a), s);        // adaptation
        vth = __fadd_rn(1.0f, __fmul_rn(b_c, a));     // adaptive threshold
        ps  = s;
        return s;
    };

    loadChunk(0);
    const int cbase = tid * STRIDE;

    #pragma unroll 1
    for (int k = 0; k < NCHUNK; ++k) {
        stage();                       // ds_write ld -> inbuf (waits chunk-k loads)
        if (k > 0) readout(k - 1);     // drain previous spike tile (coalesced stores)
        __syncthreads();               // inbuf ready; outbuf readout done
        if (k + 1 < NCHUNK) loadChunk(k + 1);  // prefetch: in flight during compute
        #pragma unroll
        for (int t4 = 0; t4 < CHUNK / 4; ++t4) {
            float4 xq = *(const float4*)&inbuf[cbase + t4 * 4];
            float4 sv;
            sv.x = step(xq.x);
            sv.y = step(xq.y);
            sv.z = step(xq.z);
            sv.w = step(xq.w);
            *(float4*)&outbuf[cbase + t4 * 4] = sv;
        }
        __syncthreads();               // outbuf full; inbuf consumed; loads landed
    }
    readout(NCHUNK - 1);
}

extern "C" void kernel_launch(void* const* d_in, const int* in_sizes, int n_in,
                              void* d_out, int out_size, void* d_ws, size_t ws_size,
                              hipStream_t stream) {
    const float* x    = (const float*)d_in[0];
    const float* beta = (const float*)d_in[1];
    const float* p    = (const float*)d_in[2];
    const float* b    = (const float*)d_in[3];
    float* out        = (float*)d_out;

    const int BN = 64 * 1024;  // rows
    snn_fwd<<<dim3(BN / ROWS), dim3(ROWS), 0, stream>>>(x, beta, p, b, out);
}